// Round 8
// baseline (610.316 us; speedup 1.0000x reference)
//
#include <hip/hip_runtime.h>

typedef unsigned short ushortT;
typedef ushortT ushort8 __attribute__((ext_vector_type(8)));
typedef short bf16x8 __attribute__((ext_vector_type(8)));
typedef float f32x4 __attribute__((ext_vector_type(4)));
typedef unsigned int uint32;

#define NN 40000
#define NE 512000
#define DD 128
#define RR 8
#define NSEG (NN * RR)   // 320000
#define KT 1152          // R*D + D
#define NB_SCAN 1250     // NSEG / 256

__device__ __forceinline__ float bf2f(ushortT u) { return __uint_as_float(((unsigned)u) << 16); }
__device__ __forceinline__ ushortT f2bf(float f) {
  unsigned u = __float_as_uint(f);
  unsigned r = (u + 0x7fffu + ((u >> 16) & 1u)) >> 16;   // RNE
  return (ushortT)r;
}

// ---------------- CSR build: count / scan / fill ----------------
__global__ void count_kernel(const int* __restrict__ dst, const int* __restrict__ et,
                             int* __restrict__ cnt) {
  int e = blockIdx.x * 256 + threadIdx.x;
  if (e < NE) atomicAdd(&cnt[dst[e] * RR + et[e]], 1);
}

__global__ void scan1_kernel(const int* __restrict__ cnt, int* __restrict__ offs,
                             int* __restrict__ bsum) {
  __shared__ int s[256];
  int tid = threadIdx.x, gid = blockIdx.x * 256 + tid;
  int v = cnt[gid];            // NSEG = 1250*256 exact
  s[tid] = v; __syncthreads();
  for (int o = 1; o < 256; o <<= 1) {
    int t = (tid >= o) ? s[tid - o] : 0;
    __syncthreads(); s[tid] += t; __syncthreads();
  }
  offs[gid] = s[tid] - v;      // block-local exclusive
  if (tid == 255) bsum[blockIdx.x] = s[255];
}

__global__ void scan2_kernel(int* __restrict__ bsum) {
  __shared__ int s[256];
  __shared__ int carry, tot;
  int tid = threadIdx.x;
  if (tid == 0) carry = 0;
  __syncthreads();
  for (int base = 0; base < NB_SCAN; base += 256) {
    int i = base + tid;
    int v = (i < NB_SCAN) ? bsum[i] : 0;
    s[tid] = v; __syncthreads();
    for (int o = 1; o < 256; o <<= 1) {
      int t = (tid >= o) ? s[tid - o] : 0;
      __syncthreads(); s[tid] += t; __syncthreads();
    }
    if (i < NB_SCAN) bsum[i] = s[tid] - v + carry;
    if (tid == 255) tot = s[255];
    __syncthreads();
    if (tid == 0) carry += tot;
    __syncthreads();
  }
}

__global__ void scan3_kernel(int* __restrict__ offs, const int* __restrict__ bsum,
                             const int* __restrict__ cnt, int* __restrict__ cursor) {
  int gid = blockIdx.x * 256 + threadIdx.x;
  int v = offs[gid] + bsum[blockIdx.x];
  offs[gid] = v;
  cursor[gid] = v;
  if (gid == NSEG - 1) offs[NSEG] = v + cnt[gid];
}

// fill: edata = src | (et<<16)  (src < 65536), wgt = 1/cnt[seg]
__global__ void fill_kernel(const int* __restrict__ src, const int* __restrict__ dst,
                            const int* __restrict__ et, const int* __restrict__ cnt,
                            int* __restrict__ cursor, int* __restrict__ edata,
                            float* __restrict__ wgt) {
  int e = blockIdx.x * 256 + threadIdx.x;
  if (e >= NE) return;
  int r = et[e];
  int seg = dst[e] * RR + r;
  int slot = atomicAdd(&cursor[seg], 1);
  edata[slot] = src[e] | (r << 16);
  wgt[slot] = 1.0f / (float)cnt[seg];
}

// ---------------- h0 = prelu(num_x*lin_w + lin_b) + x  -> bf16 ----------------
__global__ void init_h_kernel(const float* __restrict__ num_x, const float* __restrict__ x,
                              const float* __restrict__ lin_w, const float* __restrict__ lin_b,
                              const float* __restrict__ a0, ushortT* __restrict__ h) {
  int idx = blockIdx.x * 256 + threadIdx.x;
  if (idx >= NN * DD) return;
  int n = idx >> 7, d = idx & 127;
  float v = fmaf(num_x[n], lin_w[d], lin_b[d]);
  v = v >= 0.f ? v : a0[d] * v;
  h[idx] = f2bf(v + x[idx]);
}

// ---------------- Wall6[layer][j][k] bf16: col j of [W_0|..|W_7|root], k = input dim ----------------
__global__ void build_wall_kernel(const float* __restrict__ bases, const float* __restrict__ comp,
                                  const float* __restrict__ root, ushortT* __restrict__ Wall6) {
  int idx = blockIdx.x * 256 + threadIdx.x;  // over 6*KT*DD
  if (idx >= 6 * KT * DD) return;
  int layer = idx / (KT * DD);
  int rem = idx - layer * (KT * DD);
  int j = rem >> 7, k = rem & 127;
  float s;
  if (j < RR * DD) {
    int r = j >> 7, o = j & 127;
    const float* C = comp + layer * 64 + r * 8;
    const float* B = bases + ((size_t)layer * 8 * DD + 0) * DD * DD / DD;  // base of layer
    s = 0.f;
#pragma unroll
    for (int b = 0; b < 8; ++b)
      s += C[b] * bases[(((size_t)layer * 8 + b) * DD + k) * DD + o];
  } else {
    s = root[((size_t)layer * DD + k) * DD + (j - RR * DD)];
  }
  Wall6[idx] = f2bf(s);
}

// ---------------- gemmZ: Z[n, 0:1152] = h[n, :] @ Wall   (K=128, no k-loop) ----------------
// grid 625*9; nblk = bid/625 (B-tile stays hot per XCD), mblk = bid%625.
__global__ __launch_bounds__(256)
void gemmZ_kernel(const ushortT* __restrict__ h, const ushortT* __restrict__ Wall,
                  ushortT* __restrict__ Z) {
  __shared__ ushortT As[64 * 128];    // 16 KB, row pitch 256 B
  __shared__ ushortT Bs[128 * 128];   // 32 KB
  int bid = blockIdx.x;
  int nblk = bid / 625, mblk = bid - nblk * 625;
  int n0 = mblk * 64;
  int tid = threadIdx.x, lane = tid & 63, wv = tid >> 6;
  int wr = wv >> 1, wc = wv & 1;
  // ---- stage A: 4 issues/wave, 4 rows each ----
#pragma unroll
  for (int j = 0; j < 4; ++j) {
    int baser = wv * 16 + j * 4;
    int row = baser + (lane >> 4);
    int p = (lane & 15) ^ (row & 7);
    const ushortT* g = h + (size_t)(n0 + row) * DD + p * 8;
    __builtin_amdgcn_global_load_lds(
        (const __attribute__((address_space(1))) void*)g,
        (__attribute__((address_space(3))) void*)&As[baser * 128], 16, 0, 0);
  }
  // ---- stage B: 8 issues/wave, 4 cols each ----
#pragma unroll
  for (int j = 0; j < 8; ++j) {
    int basec = wv * 32 + j * 4;
    int col = basec + (lane >> 4);
    int p = (lane & 15) ^ (col & 7);
    const ushortT* g = Wall + (size_t)(nblk * 128 + col) * DD + p * 8;
    __builtin_amdgcn_global_load_lds(
        (const __attribute__((address_space(1))) void*)g,
        (__attribute__((address_space(3))) void*)&Bs[basec * 128], 16, 0, 0);
  }
  f32x4 acc[2][4];
#pragma unroll
  for (int m = 0; m < 2; ++m)
#pragma unroll
    for (int n = 0; n < 4; ++n) acc[m][n] = (f32x4){0.f, 0.f, 0.f, 0.f};
  __syncthreads();
#pragma unroll
  for (int kk = 0; kk < 4; ++kk) {
    int ko2 = kk * 64 + ((lane >> 4) << 4);   // byte offset of k within row
    bf16x8 a[2], b[4];
#pragma unroll
    for (int m = 0; m < 2; ++m) {
      int row = wr * 32 + m * 16 + (lane & 15);
      int off = ((row << 8) + ko2) ^ ((row & 7) << 4);
      a[m] = *(const bf16x8*)((const char*)As + off);
    }
#pragma unroll
    for (int n = 0; n < 4; ++n) {
      int col = wc * 64 + n * 16 + (lane & 15);
      int off = ((col << 8) + ko2) ^ ((col & 7) << 4);
      b[n] = *(const bf16x8*)((const char*)Bs + off);
    }
#pragma unroll
    for (int m = 0; m < 2; ++m)
#pragma unroll
      for (int n = 0; n < 4; ++n)
        acc[m][n] = __builtin_amdgcn_mfma_f32_16x16x32_bf16(a[m], b[n], acc[m][n], 0, 0, 0);
  }
  // epilogue: D layout col=lane&15, row=(lane>>4)*4+reg  [m89]
#pragma unroll
  for (int m = 0; m < 2; ++m) {
    int row = n0 + wr * 32 + m * 16 + (lane >> 4) * 4;
#pragma unroll
    for (int n = 0; n < 4; ++n) {
      int col = nblk * 128 + wc * 64 + n * 16 + (lane & 15);
#pragma unroll
      for (int q = 0; q < 4; ++q)
        Z[(size_t)(row + q) * KT + col] = f2bf(acc[m][n][q]);
    }
  }
}

// ---------------- aggE: h'[n,:] = prelu( sum_e w_e*Z[src_e, et*128 + :] + Z[n,1024+:] + bias ) ----
// 16 lanes per node (8 cols each), 2-edge unroll. Grid NN*16/256 = 2500 exact.
__global__ __launch_bounds__(256)
void aggE_kernel(const int* __restrict__ offs, const int* __restrict__ edata,
                 const float* __restrict__ wgt, const ushortT* __restrict__ Z,
                 const float* __restrict__ bias, const float* __restrict__ slope,
                 ushortT* __restrict__ hnew) {
  int n = (blockIdx.x * 256 + threadIdx.x) >> 4;
  int l = threadIdx.x & 15;
  int beg = offs[n * 8], end = offs[n * 8 + 8];
  float a[8] = {0.f, 0.f, 0.f, 0.f, 0.f, 0.f, 0.f, 0.f};
  int e = beg;
  for (; e + 2 <= end; e += 2) {
    int ed0 = edata[e], ed1 = edata[e + 1];
    float w0 = wgt[e], w1 = wgt[e + 1];
    const ushortT* p0 = Z + (size_t)(ed0 & 0xFFFF) * KT + ((ed0 >> 16) << 7) + l * 8;
    const ushortT* p1 = Z + (size_t)(ed1 & 0xFFFF) * KT + ((ed1 >> 16) << 7) + l * 8;
    ushort8 v0 = *(const ushort8*)p0;
    ushort8 v1 = *(const ushort8*)p1;
#pragma unroll
    for (int j = 0; j < 8; ++j)
      a[j] = fmaf(w1, bf2f(v1[j]), fmaf(w0, bf2f(v0[j]), a[j]));
  }
  if (e < end) {
    int ed0 = edata[e];
    float w0 = wgt[e];
    const ushortT* p0 = Z + (size_t)(ed0 & 0xFFFF) * KT + ((ed0 >> 16) << 7) + l * 8;
    ushort8 v0 = *(const ushort8*)p0;
#pragma unroll
    for (int j = 0; j < 8; ++j) a[j] = fmaf(w0, bf2f(v0[j]), a[j]);
  }
  // root + bias + prelu
  ushort8 vr = *(const ushort8*)(Z + (size_t)n * KT + RR * DD + l * 8);
  ushort8 r;
#pragma unroll
  for (int j = 0; j < 8; ++j) {
    int c = l * 8 + j;
    float v = a[j] + bf2f(vr[j]) + bias[c];
    v = v >= 0.f ? v : slope[c] * v;
    r[j] = f2bf(v);
  }
  *(ushort8*)&hnew[(size_t)n * DD + l * 8] = r;
}

// ---------------- W7t[c][k] fp32: c<24 -> rel (r=c/3), c in 24..26 -> root7 ----------------
__global__ void build_w7t_kernel(const float* __restrict__ bases7, const float* __restrict__ comp7,
                                 const float* __restrict__ root7, float* __restrict__ W7t) {
  int idx = blockIdx.x * 256 + threadIdx.x;
  if (idx >= 27 * DD) return;
  int c = idx >> 7, k = idx & 127;
  float s;
  if (c < 24) {
    int r = c / 3, cc = c - r * 3;
    s = 0.f;
#pragma unroll
    for (int b = 0; b < 8; ++b) s += comp7[r * 8 + b] * bases7[(b * DD + k) * 3 + cc];
  } else {
    s = root7[k * 3 + (c - 24)];
  }
  W7t[idx] = s;
}

// ---------------- gemm7: Z7[n][c] = h[n,:] . W7t[c,:]  (c<27), fp32 out ----------------
__global__ __launch_bounds__(256)
void gemm7_kernel(const ushortT* __restrict__ h, const float* __restrict__ W7t,
                  float* __restrict__ Z7) {
  int t = blockIdx.x * 256 + threadIdx.x;   // grid 5000 = NN*32/256
  int n = t >> 5, c = t & 31;
  if (c >= 27) return;
  const ushortT* hp = h + (size_t)n * DD;
  const float* w = W7t + c * DD;
  float s = 0.f;
#pragma unroll
  for (int kb = 0; kb < 16; ++kb) {
    ushort8 v = *(const ushort8*)(hp + kb * 8);
#pragma unroll
    for (int j = 0; j < 8; ++j) s = fmaf(bf2f(v[j]), w[kb * 8 + j], s);
  }
  Z7[n * 32 + c] = s;
}

// ---------------- agg7: out[n] = logsoftmax( sum_e w_e*Z7[src][et*3+c] + Z7[n][24+c] + bias7 ) ----
// 16 lanes per node, edges strided across lanes. Grid 2500.
__global__ __launch_bounds__(256)
void agg7_kernel(const int* __restrict__ offs, const int* __restrict__ edata,
                 const float* __restrict__ wgt, const float* __restrict__ Z7,
                 const float* __restrict__ bias7, float* __restrict__ out) {
  int n = (blockIdx.x * 256 + threadIdx.x) >> 4;
  int l = threadIdx.x & 15;
  int beg = offs[n * 8], end = offs[n * 8 + 8];
  float a0 = 0.f, a1 = 0.f, a2 = 0.f;
  for (int e = beg + l; e < end; e += 16) {
    int ed = edata[e];
    float w = wgt[e];
    const float* p = Z7 + (size_t)(ed & 0xFFFF) * 32 + (ed >> 16) * 3;
    a0 = fmaf(w, p[0], a0);
    a1 = fmaf(w, p[1], a1);
    a2 = fmaf(w, p[2], a2);
  }
#pragma unroll
  for (int o = 1; o < 16; o <<= 1) {
    a0 += __shfl_xor(a0, o, 16);
    a1 += __shfl_xor(a1, o, 16);
    a2 += __shfl_xor(a2, o, 16);
  }
  if (l == 0) {
    const float* zr = Z7 + (size_t)n * 32 + 24;
    float l0 = a0 + zr[0] + bias7[0];
    float l1 = a1 + zr[1] + bias7[1];
    float l2 = a2 + zr[2] + bias7[2];
    float m = fmaxf(l0, fmaxf(l1, l2));
    float lse = m + logf(expf(l0 - m) + expf(l1 - m) + expf(l2 - m));
    out[n * 3 + 0] = l0 - lse;
    out[n * 3 + 1] = l1 - lse;
    out[n * 3 + 2] = l2 - lse;
  }
}

extern "C" void kernel_launch(void* const* d_in, const int* in_sizes, int n_in,
                              void* d_out, int out_size, void* d_ws, size_t ws_size,
                              hipStream_t stream) {
  const float* num_x  = (const float*)d_in[0];
  const float* x      = (const float*)d_in[1];
  const int*   eidx   = (const int*)d_in[2];
  const int*   etype  = (const int*)d_in[3];
  const float* lin_w  = (const float*)d_in[4];
  const float* lin_b  = (const float*)d_in[5];
  const float* prelu  = (const float*)d_in[6];
  const float* bases  = (const float*)d_in[7];
  const float* comp   = (const float*)d_in[8];
  const float* root   = (const float*)d_in[9];
  const float* bias   = (const float*)d_in[10];
  const float* bases7 = (const float*)d_in[11];
  const float* comp7  = (const float*)d_in[12];
  const float* root7  = (const float*)d_in[13];
  const float* bias7  = (const float*)d_in[14];
  const int* srcv = eidx;
  const int* dstv = eidx + NE;
  float* out = (float*)d_out;

  char* p = (char*)d_ws;
  auto alloc = [&](size_t bytes) { char* q = p; p += (bytes + 255) & ~(size_t)255; return q; };
  int*     counts = (int*)alloc((size_t)NSEG * 4);
  int*     offs   = (int*)alloc((size_t)(NSEG + 1) * 4);
  int*     cursor = (int*)alloc((size_t)NSEG * 4);
  int*     bsum   = (int*)alloc((size_t)NB_SCAN * 4);
  int*     edata  = (int*)alloc((size_t)NE * 4);
  float*   wgt    = (float*)alloc((size_t)NE * 4);
  ushortT* h0     = (ushortT*)alloc((size_t)NN * DD * 2);
  ushortT* h1     = (ushortT*)alloc((size_t)NN * DD * 2);
  ushortT* Z      = (ushortT*)alloc((size_t)NN * KT * 2);     // 92 MB
  ushortT* Wall6  = (ushortT*)alloc((size_t)6 * KT * DD * 2);
  float*   W7t    = (float*)alloc((size_t)27 * DD * 4);
  float*   Z7     = (float*)alloc((size_t)NN * 32 * 4);
  if (ws_size < (size_t)(p - (char*)d_ws)) return;  // ~110 MB needed

  // CSR build (structure-only, once per call)
  hipMemsetAsync(counts, 0, (size_t)NSEG * 4, stream);
  count_kernel<<<NE / 256, 256, 0, stream>>>(dstv, etype, counts);
  scan1_kernel<<<NB_SCAN, 256, 0, stream>>>(counts, offs, bsum);
  scan2_kernel<<<1, 256, 0, stream>>>(bsum);
  scan3_kernel<<<NB_SCAN, 256, 0, stream>>>(offs, bsum, counts, cursor);
  fill_kernel<<<NE / 256, 256, 0, stream>>>(srcv, dstv, etype, counts, cursor, edata, wgt);

  init_h_kernel<<<(NN * DD + 255) / 256, 256, 0, stream>>>(num_x, x, lin_w, lin_b, prelu, h0);
  build_wall_kernel<<<(6 * KT * DD + 255) / 256, 256, 0, stream>>>(bases, comp, root, Wall6);
  build_w7t_kernel<<<(27 * DD + 255) / 256, 256, 0, stream>>>(bases7, comp7, root7, W7t);

  ushortT* hin = h0;
  ushortT* hout = h1;
  for (int layer = 0; layer < 6; ++layer) {
    gemmZ_kernel<<<625 * 9, 256, 0, stream>>>(hin, Wall6 + (size_t)layer * KT * DD, Z);
    aggE_kernel<<<NN * 16 / 256, 256, 0, stream>>>(offs, edata, wgt, Z, bias + layer * DD,
                                                   prelu + (layer + 1) * DD, hout);
    ushortT* t = hin; hin = hout; hout = t;
  }
  gemm7_kernel<<<NN * 32 / 256, 256, 0, stream>>>(hin, W7t, Z7);
  agg7_kernel<<<NN * 16 / 256, 256, 0, stream>>>(offs, edata, wgt, Z7, bias7, out);
}

// Round 9
// 495.719 us; speedup vs baseline: 1.2312x; 1.2312x over previous
//
#include <hip/hip_runtime.h>

typedef unsigned short ushortT;
typedef ushortT ushort8 __attribute__((ext_vector_type(8)));
typedef short bf16x8 __attribute__((ext_vector_type(8)));
typedef float f32x4 __attribute__((ext_vector_type(4)));
typedef unsigned int uint32;

#define NN 40000
#define NE 512000
#define DD 128
#define RR 8
#define NSEG (NN * RR)   // 320000
#define KT 1152          // R*D + D
#define NB_SCAN 1250     // NSEG / 256

__device__ __forceinline__ float bf2f(ushortT u) { return __uint_as_float(((unsigned)u) << 16); }
__device__ __forceinline__ ushortT f2bf(float f) {
  unsigned u = __float_as_uint(f);
  unsigned r = (u + 0x7fffu + ((u >> 16) & 1u)) >> 16;   // RNE
  return (ushortT)r;
}

// ---------------- CSR build: count / scan / fill ----------------
__global__ void count_kernel(const int* __restrict__ dst, const int* __restrict__ et,
                             int* __restrict__ cnt) {
  int e = blockIdx.x * 256 + threadIdx.x;
  if (e < NE) atomicAdd(&cnt[dst[e] * RR + et[e]], 1);
}

__global__ void scan1_kernel(const int* __restrict__ cnt, int* __restrict__ offs,
                             int* __restrict__ bsum) {
  __shared__ int s[256];
  int tid = threadIdx.x, gid = blockIdx.x * 256 + tid;
  int v = cnt[gid];            // NSEG = 1250*256 exact
  s[tid] = v; __syncthreads();
  for (int o = 1; o < 256; o <<= 1) {
    int t = (tid >= o) ? s[tid - o] : 0;
    __syncthreads(); s[tid] += t; __syncthreads();
  }
  offs[gid] = s[tid] - v;      // block-local exclusive
  if (tid == 255) bsum[blockIdx.x] = s[255];
}

__global__ void scan2_kernel(int* __restrict__ bsum) {
  __shared__ int s[256];
  __shared__ int carry, tot;
  int tid = threadIdx.x;
  if (tid == 0) carry = 0;
  __syncthreads();
  for (int base = 0; base < NB_SCAN; base += 256) {
    int i = base + tid;
    int v = (i < NB_SCAN) ? bsum[i] : 0;
    s[tid] = v; __syncthreads();
    for (int o = 1; o < 256; o <<= 1) {
      int t = (tid >= o) ? s[tid - o] : 0;
      __syncthreads(); s[tid] += t; __syncthreads();
    }
    if (i < NB_SCAN) bsum[i] = s[tid] - v + carry;
    if (tid == 255) tot = s[255];
    __syncthreads();
    if (tid == 0) carry += tot;
    __syncthreads();
  }
}

__global__ void scan3_kernel(int* __restrict__ offs, const int* __restrict__ bsum,
                             const int* __restrict__ cnt, int* __restrict__ cursor) {
  int gid = blockIdx.x * 256 + threadIdx.x;
  int v = offs[gid] + bsum[blockIdx.x];
  offs[gid] = v;
  cursor[gid] = v;
  if (gid == NSEG - 1) offs[NSEG] = v + cnt[gid];
}

__global__ void fill_kernel(const int* __restrict__ src, const int* __restrict__ dst,
                            const int* __restrict__ et, int* __restrict__ cursor,
                            int* __restrict__ srcs) {
  int e = blockIdx.x * 256 + threadIdx.x;
  if (e >= NE) return;
  int seg = dst[e] * RR + et[e];
  int slot = atomicAdd(&cursor[seg], 1);
  srcs[slot] = src[e];
}

// ---------------- h0 = prelu(num_x*lin_w + lin_b) + x  -> bf16 ----------------
__global__ void init_h_kernel(const float* __restrict__ num_x, const float* __restrict__ x,
                              const float* __restrict__ lin_w, const float* __restrict__ lin_b,
                              const float* __restrict__ a0, ushortT* __restrict__ h) {
  int idx = blockIdx.x * 256 + threadIdx.x;
  if (idx >= NN * DD) return;
  int n = idx >> 7, d = idx & 127;
  float v = fmaf(num_x[n], lin_w[d], lin_b[d]);
  v = v >= 0.f ? v : a0[d] * v;
  h[idx] = f2bf(v + x[idx]);
}

// ---------------- Wt6[layer][j][k] bf16 (transposed, K-contiguous), all 6 layers ----------------
__global__ void build_w_kernel(const float* __restrict__ bases, const float* __restrict__ comp,
                               const float* __restrict__ root, ushortT* __restrict__ Wt6) {
  int idx = blockIdx.x * 256 + threadIdx.x;  // over 6*DD*KT
  if (idx >= 6 * DD * KT) return;
  int layer = idx / (DD * KT);
  int rem = idx - layer * (DD * KT);
  int j = rem / KT, k = rem - j * KT;
  const float* B  = bases + (size_t)layer * 8 * DD * DD;
  const float* C  = comp + layer * RR * 8;
  const float* Rt = root + (size_t)layer * DD * DD;
  float s;
  if (k < RR * DD) {
    int r = k >> 7, i = k & 127;
    s = 0.f;
#pragma unroll
    for (int b = 0; b < 8; ++b) s += C[r * 8 + b] * B[(b * DD + i) * DD + j];
  } else {
    s = Rt[(k - RR * DD) * DD + j];
  }
  Wt6[idx] = f2bf(s);
}

// ---------------- aggregation v3 (R5-proven): 8 lanes/segment, 32 segments/block, 2-edge unroll ----
__global__ __launch_bounds__(256)
void agg_kernel(const int* __restrict__ offs, const int* __restrict__ srcs,
                const ushortT* __restrict__ h, ushortT* __restrict__ Xagg) {
  int seg = blockIdx.x * 32 + (threadIdx.x >> 3);   // NSEG/32 blocks exact
  int l = threadIdx.x & 7;                           // 16 cols (32 B) per lane
  int beg = offs[seg], end = offs[seg + 1];
  float a[16];
#pragma unroll
  for (int j = 0; j < 16; ++j) a[j] = 0.f;
  int e = beg;
  for (; e + 2 <= end; e += 2) {
    int s0 = srcs[e], s1 = srcs[e + 1];
    const ushortT* p0 = &h[(size_t)s0 * DD + l * 16];
    const ushortT* p1 = &h[(size_t)s1 * DD + l * 16];
    ushort8 v00 = *(const ushort8*)p0;
    ushort8 v01 = *(const ushort8*)(p0 + 8);
    ushort8 v10 = *(const ushort8*)p1;
    ushort8 v11 = *(const ushort8*)(p1 + 8);
#pragma unroll
    for (int j = 0; j < 8; ++j) {
      a[j]     += bf2f(v00[j]) + bf2f(v10[j]);
      a[8 + j] += bf2f(v01[j]) + bf2f(v11[j]);
    }
  }
  if (e < end) {
    int s0 = srcs[e];
    const ushortT* p0 = &h[(size_t)s0 * DD + l * 16];
    ushort8 v00 = *(const ushort8*)p0;
    ushort8 v01 = *(const ushort8*)(p0 + 8);
#pragma unroll
    for (int j = 0; j < 8; ++j) {
      a[j]     += bf2f(v00[j]);
      a[8 + j] += bf2f(v01[j]);
    }
  }
  float inv = (end > beg) ? 1.0f / (float)(end - beg) : 1.0f;
  ushort8 r0, r1;
#pragma unroll
  for (int j = 0; j < 8; ++j) {
    r0[j] = f2bf(a[j] * inv);
    r1[j] = f2bf(a[8 + j] * inv);
  }
  ushortT* op = &Xagg[(size_t)seg * DD + l * 16];
  *(ushort8*)op = r0;
  *(ushort8*)(op + 8) = r1;
}

// ---------------- GEMM: hout = prelu( [Xagg|h] @ Wt^T + bias ), bf16 MFMA ----------------
// BM=64 (625 blocks exact), BN=128, BK=128 -> 9 k-steps (half the barrier drains of BK=64).
// LDS 48 KB single-buffered (3 blocks/CU). Swizzle: source chunk p=(lane&15)^(row&7),
// read off = row*256 + ko ^ ((row&7)<<4)  (2 lanes/bank after swizzle = free).
__global__ __launch_bounds__(256)
void gemm_kernel(const ushortT* __restrict__ Xagg, const ushortT* __restrict__ h,
                 const ushortT* __restrict__ Wt, const float* __restrict__ bias,
                 const float* __restrict__ slope, ushortT* __restrict__ hout) {
  __shared__ ushortT As[64 * 128];     // 16 KB, row pitch 256 B
  __shared__ ushortT Bs[128 * 128];    // 32 KB
  int tid = threadIdx.x, lane = tid & 63, wv = tid >> 6;
  int wr = wv >> 1, wc = wv & 1;
  int n0 = blockIdx.x * 64;
  int l4 = lane >> 4;     // 0..3: row-in-issue
  int lp = lane & 15;     // 0..15: dest 16B chunk slot
  f32x4 acc[2][4];
#pragma unroll
  for (int m = 0; m < 2; ++m)
#pragma unroll
    for (int n = 0; n < 4; ++n) acc[m][n] = (f32x4){0.f, 0.f, 0.f, 0.f};

  for (int t = 0; t < 9; ++t) {
    int kc = t * 128;
    // ---- stage A: wave wv stages rows wv*16 .. wv*16+15, 4 issues of 4 rows ----
#pragma unroll
    for (int j = 0; j < 4; ++j) {
      int baser = wv * 16 + j * 4;
      int row = baser + l4;
      int p = lp ^ (row & 7);                 // pre-swizzled source chunk
      const ushortT* g;
      if (kc < RR * DD) g = Xagg + (size_t)(n0 + row) * 1024 + kc + p * 8;
      else              g = h + (size_t)(n0 + row) * DD + p * 8;
      __builtin_amdgcn_global_load_lds(
          (const __attribute__((address_space(1))) void*)g,
          (__attribute__((address_space(3))) void*)&As[baser * 128], 16, 0, 0);
    }
    // ---- stage B: wave wv stages cols wv*32 .. wv*32+31, 8 issues of 4 cols ----
#pragma unroll
    for (int j = 0; j < 8; ++j) {
      int basec = wv * 32 + j * 4;
      int col = basec + l4;
      int p = lp ^ (col & 7);
      const ushortT* g = Wt + (size_t)col * KT + kc + p * 8;
      __builtin_amdgcn_global_load_lds(
          (const __attribute__((address_space(1))) void*)g,
          (__attribute__((address_space(3))) void*)&Bs[basec * 128], 16, 0, 0);
    }
    __syncthreads();   // compiler drains vmcnt(0) before s_barrier
#pragma unroll
    for (int kk = 0; kk < 4; ++kk) {
      int ko2 = kk * 64 + (l4 << 4);   // byte offset of k within row
      bf16x8 a[2], b[4];
#pragma unroll
      for (int m = 0; m < 2; ++m) {
        int row = wr * 32 + m * 16 + (lane & 15);
        int off = ((row << 8) + ko2) ^ ((row & 7) << 4);
        a[m] = *(const bf16x8*)((const char*)As + off);
      }
#pragma unroll
      for (int n = 0; n < 4; ++n) {
        int col = wc * 64 + n * 16 + (lane & 15);
        int off = ((col << 8) + ko2) ^ ((col & 7) << 4);
        b[n] = *(const bf16x8*)((const char*)Bs + off);
      }
#pragma unroll
      for (int m = 0; m < 2; ++m)
#pragma unroll
        for (int n = 0; n < 4; ++n)
          acc[m][n] = __builtin_amdgcn_mfma_f32_16x16x32_bf16(a[m], b[n], acc[m][n], 0, 0, 0);
    }
    __syncthreads();
  }
  // epilogue: D layout col=lane&15, row=(lane>>4)*4+reg  [m89]
#pragma unroll
  for (int m = 0; m < 2; ++m) {
    int row = n0 + wr * 32 + m * 16 + (lane >> 4) * 4;
#pragma unroll
    for (int n = 0; n < 4; ++n) {
      int col = wc * 64 + n * 16 + (lane & 15);
      float bcol = bias[col], scol = slope[col];
#pragma unroll
      for (int q = 0; q < 4; ++q) {
        float v = acc[m][n][q] + bcol;
        v = v >= 0.f ? v : scol * v;
        hout[(size_t)(row + q) * DD + col] = f2bf(v);
      }
    }
  }
}

// ---------------- conv7 weight [1152][3] fp32 ----------------
__global__ void build_w7_kernel(const float* __restrict__ bases7, const float* __restrict__ comp7,
                                const float* __restrict__ root7, float* __restrict__ W7) {
  int idx = blockIdx.x * 256 + threadIdx.x;
  if (idx >= KT * 3) return;
  int row = idx / 3, c = idx - row * 3;
  if (row < RR * DD) {
    int r = row >> 7, i = row & 127;
    float s = 0.f;
#pragma unroll
    for (int b = 0; b < 8; ++b) s += comp7[r * 8 + b] * bases7[(b * DD + i) * 3 + c];
    W7[idx] = s;
  } else {
    W7[idx] = root7[(row - RR * DD) * 3 + c];
  }
}

// ---------------- conv7 + log_softmax: one wave per node, reads Xagg ----------------
__global__ void conv7_kernel(const ushortT* __restrict__ Xagg, const ushortT* __restrict__ h,
                             const float* __restrict__ W7, const float* __restrict__ bias7,
                             float* __restrict__ out) {
  int gw = (blockIdx.x * 256 + threadIdx.x) >> 6;
  if (gw >= NN) return;
  int lane = threadIdx.x & 63;
  float a0 = 0.f, a1 = 0.f, a2 = 0.f;
#pragma unroll
  for (int i = 0; i < 2; ++i) {
    int k0 = i * 512 + lane * 8;
    ushort8 v = *(const ushort8*)&Xagg[(size_t)gw * 1024 + k0];
#pragma unroll
    for (int j = 0; j < 8; ++j) {
      float xx = bf2f(v[j]);
      const float* w = &W7[(k0 + j) * 3];
      a0 = fmaf(xx, w[0], a0); a1 = fmaf(xx, w[1], a1); a2 = fmaf(xx, w[2], a2);
    }
  }
  {
    uint32 v = *(const uint32*)&h[(size_t)gw * DD + lane * 2];
    float x0 = __uint_as_float(v << 16), x1 = __uint_as_float(v & 0xffff0000u);
    int k0 = 1024 + lane * 2;
    const float* w0 = &W7[k0 * 3];
    const float* w1 = &W7[(k0 + 1) * 3];
    a0 = fmaf(x0, w0[0], a0); a1 = fmaf(x0, w0[1], a1); a2 = fmaf(x0, w0[2], a2);
    a0 = fmaf(x1, w1[0], a0); a1 = fmaf(x1, w1[1], a1); a2 = fmaf(x1, w1[2], a2);
  }
#pragma unroll
  for (int o = 32; o > 0; o >>= 1) {
    a0 += __shfl_down(a0, o);
    a1 += __shfl_down(a1, o);
    a2 += __shfl_down(a2, o);
  }
  if (lane == 0) {
    float l0 = a0 + bias7[0], l1 = a1 + bias7[1], l2 = a2 + bias7[2];
    float m = fmaxf(l0, fmaxf(l1, l2));
    float lse = m + logf(expf(l0 - m) + expf(l1 - m) + expf(l2 - m));
    out[gw * 3 + 0] = l0 - lse;
    out[gw * 3 + 1] = l1 - lse;
    out[gw * 3 + 2] = l2 - lse;
  }
}

extern "C" void kernel_launch(void* const* d_in, const int* in_sizes, int n_in,
                              void* d_out, int out_size, void* d_ws, size_t ws_size,
                              hipStream_t stream) {
  const float* num_x  = (const float*)d_in[0];
  const float* x      = (const float*)d_in[1];
  const int*   eidx   = (const int*)d_in[2];
  const int*   etype  = (const int*)d_in[3];
  const float* lin_w  = (const float*)d_in[4];
  const float* lin_b  = (const float*)d_in[5];
  const float* prelu  = (const float*)d_in[6];
  const float* bases  = (const float*)d_in[7];
  const float* comp   = (const float*)d_in[8];
  const float* root   = (const float*)d_in[9];
  const float* bias   = (const float*)d_in[10];
  const float* bases7 = (const float*)d_in[11];
  const float* comp7  = (const float*)d_in[12];
  const float* root7  = (const float*)d_in[13];
  const float* bias7  = (const float*)d_in[14];
  const int* srcv = eidx;
  const int* dstv = eidx + NE;
  float* out = (float*)d_out;

  char* p = (char*)d_ws;
  auto alloc = [&](size_t bytes) { char* q = p; p += (bytes + 255) & ~(size_t)255; return q; };
  int*     counts = (int*)alloc((size_t)NSEG * 4);
  int*     offs   = (int*)alloc((size_t)(NSEG + 1) * 4);
  int*     cursor = (int*)alloc((size_t)NSEG * 4);
  int*     bsum   = (int*)alloc((size_t)NB_SCAN * 4);
  int*     srcs   = (int*)alloc((size_t)NE * 4);
  ushortT* h0     = (ushortT*)alloc((size_t)NN * DD * 2);
  ushortT* h1     = (ushortT*)alloc((size_t)NN * DD * 2);
  ushortT* Xagg   = (ushortT*)alloc((size_t)NN * 1024 * 2);
  ushortT* Wt6    = (ushortT*)alloc((size_t)6 * DD * KT * 2);
  float*   W7     = (float*)alloc((size_t)KT * 3 * 4);
  if (ws_size < (size_t)(p - (char*)d_ws)) return;  // ~111 MB needed

  // CSR build (structure-only, once per call)
  hipMemsetAsync(counts, 0, (size_t)NSEG * 4, stream);
  count_kernel<<<NE / 256, 256, 0, stream>>>(dstv, etype, counts);
  scan1_kernel<<<NB_SCAN, 256, 0, stream>>>(counts, offs, bsum);
  scan2_kernel<<<1, 256, 0, stream>>>(bsum);
  scan3_kernel<<<NB_SCAN, 256, 0, stream>>>(offs, bsum, counts, cursor);
  fill_kernel<<<NE / 256, 256, 0, stream>>>(srcv, dstv, etype, cursor, srcs);

  init_h_kernel<<<(NN * DD + 255) / 256, 256, 0, stream>>>(num_x, x, lin_w, lin_b, prelu, h0);
  build_w_kernel<<<(6 * DD * KT + 255) / 256, 256, 0, stream>>>(bases, comp, root, Wt6);
  build_w7_kernel<<<(KT * 3 + 255) / 256, 256, 0, stream>>>(bases7, comp7, root7, W7);

  ushortT* hin = h0;
  ushortT* hout = h1;
  for (int layer = 0; layer < 6; ++layer) {
    agg_kernel<<<NSEG / 32, 256, 0, stream>>>(offs, srcs, hin, Xagg);
    gemm_kernel<<<NN / 64, 256, 0, stream>>>(Xagg, hin, Wt6 + (size_t)layer * DD * KT,
                                             bias + layer * DD, prelu + (layer + 1) * DD, hout);
    ushortT* t = hin; hin = hout; hout = t;
  }
  agg_kernel<<<NSEG / 32, 256, 0, stream>>>(offs, srcs, hin, Xagg);
  conv7_kernel<<<NN / 4, 256, 0, stream>>>(Xagg, hin, W7, bias7, out);
}